// Round 8
// baseline (131.210 us; speedup 1.0000x reference)
//
#include <hip/hip_runtime.h>
#include <hip/hip_bf16.h>

#define B_ 2
#define T_ 2048
#define C_ 1024
#define NH_ 16
#define NKV_ 4
#define HD_ 64
#define NQKV_ 1536           // (NH + 2*NKV) * HD
#define M_ 4096              // B_ * T_

typedef __attribute__((ext_vector_type(8))) __bf16 bf16x8;
typedef __attribute__((ext_vector_type(4))) __bf16 bf16x4;
typedef __attribute__((ext_vector_type(4))) float f32x4;
typedef __attribute__((ext_vector_type(4))) unsigned int u32x4;

#define GLOAD_LDS16(gptr, lptr)                                                        \
  __builtin_amdgcn_global_load_lds(                                                    \
      (const __attribute__((address_space(1))) unsigned int*)(gptr),                   \
      (__attribute__((address_space(3))) unsigned int*)(lptr), 16, 0, 0)

// ---------------- cast x (fp32 -> bf16), 4 elems/thread ----------------
__global__ __launch_bounds__(256) void cast_x_kernel(const float* __restrict__ in,
                                                     __bf16* __restrict__ out) {
  const int i = blockIdx.x * 256 + threadIdx.x;
  const float4 v = ((const float4*)in)[i];
  bf16x4 o;
  o.x = (__bf16)v.x; o.y = (__bf16)v.y; o.z = (__bf16)v.z; o.w = (__bf16)v.w;
  ((bf16x4*)out)[i] = o;
}

// ---------- transpose + cast: in [K][N] fp32 -> out [N][K] bf16 ----------
__global__ __launch_bounds__(256) void transpose_cast_kernel(const float* __restrict__ in,
                                                             __bf16* __restrict__ out,
                                                             int K, int N) {
  __shared__ __bf16 tile[64][72];  // [n_local][k_local], padded
  const int n0 = blockIdx.x * 64, k0 = blockIdx.y * 64;
  const int tid = threadIdx.x;
  const int tr = tid >> 4, tc4 = (tid & 15) << 2;
  #pragma unroll
  for (int p = 0; p < 4; ++p) {
    const int k = k0 + p * 16 + tr;
    const float4 v = *(const float4*)&in[(size_t)k * N + n0 + tc4];
    tile[tc4 + 0][p * 16 + tr] = (__bf16)v.x;
    tile[tc4 + 1][p * 16 + tr] = (__bf16)v.y;
    tile[tc4 + 2][p * 16 + tr] = (__bf16)v.z;
    tile[tc4 + 3][p * 16 + tr] = (__bf16)v.w;
  }
  __syncthreads();
  #pragma unroll
  for (int p = 0; p < 4; ++p) {
    const int n = n0 + p * 16 + tr;
    bf16x4 o;
    o.x = tile[p * 16 + tr][tc4 + 0];
    o.y = tile[p * 16 + tr][tc4 + 1];
    o.z = tile[p * 16 + tr][tc4 + 2];
    o.w = tile[p * 16 + tr][tc4 + 3];
    *(bf16x4*)&out[(size_t)n * K + k0 + tc4] = o;
  }
}

// ---------------- RoPE cos/sin tables [T][32] fp32 ----------------
__global__ __launch_bounds__(256) void rope_table_kernel(float* __restrict__ cosT,
                                                         float* __restrict__ sinT) {
  const int idx = blockIdx.x * 256 + threadIdx.x;  // T*32 total
  const int t = idx >> 5, i = idx & 31;
  const float inv = powf(10000.0f, -(float)i * (1.0f / 32.0f));
  const float ang = (float)t * inv;
  cosT[idx] = cosf(ang);
  sinT[idx] = sinf(ang);
}

// ------- bf16 TN GEMM: A[M][K] * Bt[N][K]^T -> C[M][N] fp32 -------
// 128x128 tile, BK=64, 4 waves (2x2). Double-buffered global_load_lds (w=16):
// stage(t+1) issues BEFORE compute(t); vmcnt(0)+barrier once per tile.
// Pre-swizzled SOURCE + linear LDS dest (rule 21); reads swizzle identically.
__global__ __launch_bounds__(256) void gemm_tn_kernel(const __bf16* __restrict__ A,
                                                      const __bf16* __restrict__ Bt,
                                                      float* __restrict__ C, int N, int K) {
  __shared__ __align__(16) __bf16 lA[2][128 * 64];
  __shared__ __align__(16) __bf16 lB[2][128 * 64];
  const int tid = threadIdx.x;
  const int lane = tid & 63;
  const int wave = tid >> 6;
  const int wr = wave >> 1, wc = wave & 1;
  const int m0 = blockIdx.y * 128, n0 = blockIdx.x * 128;
  const int srow = tid >> 3, kc = tid & 7;  // staging: 8 threads/row, 16B chunks
  const int r16 = lane & 15, g = lane >> 4;
  f32x4 acc[4][4] = {};
  const int nt = K >> 6;

#define GSTAGE(buf, k0)                                                                   \
  {                                                                                       \
    _Pragma("unroll")                                                                     \
    for (int p = 0; p < 4; ++p) {                                                         \
      const int row = p * 32 + srow;                                                      \
      const int sw = (kc ^ (row & 7)) * 8;                                                \
      GLOAD_LDS16(&A[(size_t)(m0 + row) * K + (k0) + sw], &lA[buf][row * 64 + kc * 8]);   \
      GLOAD_LDS16(&Bt[(size_t)(n0 + row) * K + (k0) + sw], &lB[buf][row * 64 + kc * 8]);  \
    }                                                                                     \
  }

  GSTAGE(0, 0);
  asm volatile("s_waitcnt vmcnt(0)" ::: "memory");
  __syncthreads();
  int cur = 0;
  for (int t = 0; t < nt; ++t) {
    if (t + 1 < nt) GSTAGE(cur ^ 1, (t + 1) << 6);   // loads fly under compute
    #pragma unroll
    for (int ks = 0; ks < 64; ks += 32) {
      bf16x8 af[4], bfr[4];
      const int kch = (ks >> 3) + g;
      #pragma unroll
      for (int mi = 0; mi < 4; ++mi) {
        const int row = wr * 64 + mi * 16 + r16;
        af[mi] = *(const bf16x8*)&lA[cur][row * 64 + (kch ^ (row & 7)) * 8];
      }
      #pragma unroll
      for (int ni = 0; ni < 4; ++ni) {
        const int row = wc * 64 + ni * 16 + r16;
        bfr[ni] = *(const bf16x8*)&lB[cur][row * 64 + (kch ^ (row & 7)) * 8];
      }
      __builtin_amdgcn_s_setprio(1);
      #pragma unroll
      for (int mi = 0; mi < 4; ++mi)
        #pragma unroll
        for (int ni = 0; ni < 4; ++ni)
          acc[mi][ni] = __builtin_amdgcn_mfma_f32_16x16x32_bf16(af[mi], bfr[ni], acc[mi][ni], 0, 0, 0);
      __builtin_amdgcn_s_setprio(0);
    }
    asm volatile("s_waitcnt vmcnt(0)" ::: "memory");  // next-tile loads landed
    __syncthreads();
    cur ^= 1;
  }
  // epilogue: D layout col=lane&15, row=(lane>>4)*4+j
  #pragma unroll
  for (int mi = 0; mi < 4; ++mi) {
    const int r0 = m0 + wr * 64 + mi * 16 + g * 4;
    #pragma unroll
    for (int ni = 0; ni < 4; ++ni) {
      const int c = n0 + wc * 64 + ni * 16 + r16;
      #pragma unroll
      for (int j = 0; j < 4; ++j)
        C[(size_t)(r0 + j) * N + c] = acc[mi][ni][j];
    }
  }
#undef GSTAGE
}

// ---- RoPE on q,k (from fp32 qkv) -> Q[b][h][t][d], K[b][kvh][t][d] bf16 ----
// Q is additionally pre-scaled by 1/8 * log2(e) (softmax runs in exp2 domain).
__global__ __launch_bounds__(256) void rope_qk_kernel(const float* __restrict__ qkv,
                                                      const float* __restrict__ cosT,
                                                      const float* __restrict__ sinT,
                                                      __bf16* __restrict__ Q,
                                                      __bf16* __restrict__ Kb) {
  const int idx = blockIdx.x * 256 + threadIdx.x;  // M_*(NH+NKV)*32 total
  const int i = idx & 31;
  const int rest = idx >> 5;
  const int head = rest % (NH_ + NKV_);
  const int row = rest / (NH_ + NKV_);
  const int b = row >> 11, t = row & 2047;
  const float c = cosT[t * 32 + i], s = sinT[t * 32 + i];
  if (head < NH_) {
    const float* p = &qkv[(size_t)row * NQKV_ + head * HD_ + 2 * i];
    const float o1 = p[0] * c - p[1] * s;
    const float o2 = p[0] * s + p[1] * c;
    __bf16* q = &Q[(((size_t)b * NH_ + head) * T_ + t) * HD_ + 2 * i];
    const float qs = 0.125f * 1.44269504f;
    q[0] = (__bf16)(o1 * qs); q[1] = (__bf16)(o2 * qs);
  } else {
    const int kh = head - NH_;
    const float* p = &qkv[(size_t)row * NQKV_ + NH_ * HD_ + kh * HD_ + 2 * i];
    const float o1 = p[0] * c - p[1] * s;
    const float o2 = p[0] * s + p[1] * c;
    __bf16* k = &Kb[(((size_t)b * NKV_ + kh) * T_ + t) * HD_ + 2 * i];
    k[0] = (__bf16)o1; k[1] = (__bf16)o2;
  }
}

// ---- V transpose: qkv v-part -> Vt[b][kvh][d][t] bf16 (LDS tiled) ----
__global__ __launch_bounds__(256) void v_transpose_kernel(const float* __restrict__ qkv,
                                                          __bf16* __restrict__ Vt) {
  __shared__ __bf16 tile[64][72];  // [d][t_local], padded
  const int blk = blockIdx.x;      // B*NKV*(T/64)
  const int t0 = (blk & 31) * 64;
  const int kvh = (blk >> 5) & 3;
  const int b = blk >> 7;
  const int tid = threadIdx.x;
  const int tr = tid >> 4, c4 = (tid & 15) << 2;
  #pragma unroll
  for (int p = 0; p < 4; ++p) {
    const int t = t0 + p * 16 + tr;
    const float4 v = *(const float4*)&qkv[(size_t)(b * T_ + t) * NQKV_ + (NH_ + NKV_) * HD_ + kvh * HD_ + c4];
    tile[c4 + 0][p * 16 + tr] = (__bf16)v.x;
    tile[c4 + 1][p * 16 + tr] = (__bf16)v.y;
    tile[c4 + 2][p * 16 + tr] = (__bf16)v.z;
    tile[c4 + 3][p * 16 + tr] = (__bf16)v.w;
  }
  __syncthreads();
  #pragma unroll
  for (int p = 0; p < 4; ++p) {
    const int d = p * 16 + tr;
    bf16x4 o;
    o.x = tile[d][c4 + 0]; o.y = tile[d][c4 + 1];
    o.z = tile[d][c4 + 2]; o.w = tile[d][c4 + 3];
    *(bf16x4*)&Vt[(((size_t)b * NKV_ + kvh) * HD_ + d) * T_ + t0 + c4] = o;
  }
}

// ---- flash attention, triangle-paired, swapped-QK softmax, K/V LDS dbuf ----
// NSPLIT=2: flash-decoding style KV split. Split z processes KV tiles
// t ≡ z (mod 2) of pair {i,31-i} (strided split keeps both splits at ~16.5
// tile-activations) and writes UNNORMALIZED partial O (bf16) + (m,l) f32;
// attn_combine merges. NSPLIT=1: original single-pass path (ws fallback).
template <int NSPLIT>
__global__ __launch_bounds__(256) void attn_kernel(const __bf16* __restrict__ Q,
                                                   const __bf16* __restrict__ Kb,
                                                   const __bf16* __restrict__ Vt,
                                                   __bf16* __restrict__ Y,
                                                   __bf16* __restrict__ oPart,
                                                   float2* __restrict__ mlPart) {
  __shared__ __align__(16) __bf16 lK[2][64 * 64];   // [kv][d], swizzled
  __shared__ __align__(16) __bf16 lV[2][64 * 64];   // [d][kv], swizzled
  __shared__ __align__(16) __bf16 pP[4][16 * 64];   // per-wave [q][kv], swizzled
  const int tid = threadIdx.x;
  const int lane = tid & 63, wave = tid >> 6;
  const int r16 = lane & 15, g = lane >> 4;
  const int z = (NSPLIT > 1) ? blockIdx.y : 0;
  // bijective XCD swizzle (T1): 512 x-blocks, 8 XCDs -> 64 contiguous logical
  // ids per XCD so blocks sharing (b,kvh)'s K/V co-locate in one L2.
  const int logical = (blockIdx.x & 7) * 64 + (blockIdx.x >> 3);
  const int i = logical & 15;        // pair index: q-tiles {i, 31-i}
  const int bh = logical >> 4;
  const int b = bh >> 4, h = bh & 15;
  const int kvh = h >> 2;  // GQA rep = 4
  const __bf16* Qp = Q + ((size_t)b * NH_ + h) * T_ * HD_;
  const __bf16* Kp = Kb + ((size_t)b * NKV_ + kvh) * T_ * HD_;
  const __bf16* Vp = Vt + ((size_t)b * NKV_ + kvh) * HD_ * T_;
  const int qtile[2] = { i, 31 - i };
  const int srow = tid >> 3, kc = tid & 7;          // staging: 8x16B chunks/row

#define ASTAGE(buf, kv0_)                                                                  \
  {                                                                                        \
    _Pragma("unroll")                                                                      \
    for (int p = 0; p < 2; ++p) {                                                          \
      const int row = p * 32 + srow;                                                       \
      const int sw = (kc ^ (row & 7)) * 8;                                                 \
      GLOAD_LDS16(&Kp[(size_t)((kv0_) + row) * HD_ + sw], &lK[buf][row * 64 + kc * 8]);    \
      GLOAD_LDS16(&Vp[(size_t)row * T_ + (kv0_) + sw], &lV[buf][row * 64 + kc * 8]);       \
    }                                                                                      \
  }

  // Q fragments; pre-scaled by 1/8*log2e in rope_qk. B-operand of swapped QK.
  bf16x8 qf[2][2];
  #pragma unroll
  for (int sd = 0; sd < 2; ++sd)
    #pragma unroll
    for (int c = 0; c < 2; ++c)
      qf[sd][c] = *(const bf16x8*)&Qp[(size_t)(qtile[sd] * 64 + wave * 16 + r16) * HD_ + (c * 4 + g) * 8];

  f32x4 o[2][4] = {};
  float mS[2], lS[2];
  #pragma unroll
  for (int sd = 0; sd < 2; ++sd) { mS[sd] = -__builtin_inff(); lS[sd] = 0.0f; }

  // softmax + P-write for one side (lane owns full row q=qw+r16 of S^T)
  auto sm_side = [&](f32x4 (&s)[4], int sd) {
    // in-lane 16->1 max, max3-shaped triples (T17)
    float t0 = fmaxf(fmaxf(s[0][0], s[0][1]), s[0][2]);
    float t1 = fmaxf(fmaxf(s[0][3], s[1][0]), s[1][1]);
    float t2 = fmaxf(fmaxf(s[1][2], s[1][3]), s[2][0]);
    float t3 = fmaxf(fmaxf(s[2][1], s[2][2]), s[2][3]);
    float t4 = fmaxf(fmaxf(s[3][0], s[3][1]), s[3][2]);
    float pm = fmaxf(fmaxf(t0, t1), t2);
    pm = fmaxf(pm, fmaxf(t3, t4));
    pm = fmaxf(pm, s[3][3]);
    pm = fmaxf(pm, __shfl_xor(pm, 16));
    pm = fmaxf(pm, __shfl_xor(pm, 32));
    const bool upd = pm > mS[sd] + 8.0f;   // deferred-max (T13)
    const float nm = upd ? pm : mS[sd];
    const float sc = exp2f(mS[sd] - nm);   // ==1.0 exactly when !upd
    mS[sd] = nm;
    lS[sd] *= sc;
    if (__any(upd)) {  // redistribute sc from q=r16 layout to (g,j) layout
      #pragma unroll
      for (int j = 0; j < 4; ++j) {
        const float scj = __shfl(sc, g * 4 + j);
        #pragma unroll
        for (int nf = 0; nf < 4; ++nf) o[sd][nf][j] *= scj;
      }
    }
    // P = exp2(S-m): write each pb chunk ASAP (hides DS latency under the
    // remaining exp2s and the rs shfl chain), reduce rs after.
    float rs = 0.0f;
    #pragma unroll
    for (int ni = 0; ni < 4; ++ni) {
      bf16x4 pb;
      #pragma unroll
      for (int j = 0; j < 4; ++j) {
        const float pv = exp2f(s[ni][j] - mS[sd]);
        rs += pv;
        pb[j] = (__bf16)pv;
      }
      const int ch = 2 * ni + (g >> 1);    // row q=r16, kv-chunk, half g&1
      *(bf16x4*)&pP[wave][r16 * 64 + ((ch ^ (r16 & 7)) * 8) + (g & 1) * 4] = pb;
    }
    rs += __shfl_xor(rs, 16);
    rs += __shfl_xor(rs, 32);
    lS[sd] += rs;
  };

  const int ntiles = 32 - i;         // KV tiles needed by side B (q-tile 31-i)
  ASTAGE(0, z << 6);
  asm volatile("s_waitcnt vmcnt(0)" ::: "memory");
  __syncthreads();
  int cur = 0;

  for (int t = z; t < ntiles; t += NSPLIT) {
    const int kv0 = t << 6;
    if (t + NSPLIT < ntiles) ASTAGE(cur ^ 1, kv0 + (NSPLIT << 6));  // next owned tile

    #pragma unroll
    for (int sd = 0; sd < 2; ++sd) {
      if (sd == 0 && t > i) continue;       // side A inactive past its diagonal
      const int qw = qtile[sd] * 64 + wave * 16;

      // ---- QK^T swapped: s[ni][j] = S[kv0+ni*16+g*4+j][qw+r16] ----
      f32x4 s[4] = {};
      #pragma unroll
      for (int c = 0; c < 2; ++c) {
        bf16x8 kf[4];
        #pragma unroll
        for (int ni = 0; ni < 4; ++ni) {
          const int row = ni * 16 + r16;
          kf[ni] = *(const bf16x8*)&lK[cur][row * 64 + ((c * 4 + g) ^ (row & 7)) * 8];
        }
        __builtin_amdgcn_s_setprio(1);
        #pragma unroll
        for (int ni = 0; ni < 4; ++ni)
          s[ni] = __builtin_amdgcn_mfma_f32_16x16x32_bf16(kf[ni], qf[sd][c], s[ni], 0, 0, 0);
        __builtin_amdgcn_s_setprio(0);
      }

      // ---- causal mask (diagonal tile of this side only) ----
      if (t == ((sd == 0) ? i : (ntiles - 1))) {
        #pragma unroll
        for (int ni = 0; ni < 4; ++ni)
          #pragma unroll
          for (int j = 0; j < 4; ++j)
            if (kv0 + ni * 16 + g * 4 + j > qw + r16) s[ni][j] = -__builtin_inff();
      }

      sm_side(s, sd);
      asm volatile("s_waitcnt lgkmcnt(0)" ::: "memory");
      __builtin_amdgcn_sched_barrier(0);

      // ---- PV: O += P * V^T, 8 MFMAs ----
      __builtin_amdgcn_s_setprio(1);
      #pragma unroll
      for (int c = 0; c < 2; ++c) {
        const bf16x8 pf = *(const bf16x8*)&pP[wave][r16 * 64 + (((c * 4 + g) ^ (r16 & 7)) * 8)];
        #pragma unroll
        for (int nf = 0; nf < 4; ++nf) {
          const int row = nf * 16 + r16;
          const bf16x8 vf = *(const bf16x8*)&lV[cur][row * 64 + ((c * 4 + g) ^ (row & 7)) * 8];
          o[sd][nf] = __builtin_amdgcn_mfma_f32_16x16x32_bf16(pf, vf, o[sd][nf], 0, 0, 0);
        }
      }
      __builtin_amdgcn_s_setprio(0);
    }

    asm volatile("s_waitcnt vmcnt(0)" ::: "memory");  // next-tile loads landed
    __syncthreads();
    cur ^= 1;
  }

  if (NSPLIT == 1) {
    // ---- epilogue -> Y[b][t][h][d] bf16 (both sides); l via shfl ----
    #pragma unroll
    for (int sd = 0; sd < 2; ++sd) {
      const int qw = qtile[sd] * 64 + wave * 16;
      #pragma unroll
      for (int j = 0; j < 4; ++j) {
        const float lq = __shfl(lS[sd], g * 4 + j);
        const float inv = 1.0f / lq;
        const int tq = qw + g * 4 + j;
        #pragma unroll
        for (int nf = 0; nf < 4; ++nf) {
          const int d = nf * 16 + r16;
          Y[(((size_t)b * T_ + tq) * NH_ + h) * HD_ + d] = (__bf16)(o[sd][nf][j] * inv);
        }
      }
    }
  } else {
    // ---- epilogue -> partials: oPart[z][bh][q][d] bf16 (unnormalized), ml ----
    #pragma unroll
    for (int sd = 0; sd < 2; ++sd) {
      const int qw = qtile[sd] * 64 + wave * 16;
      if (g == 0)  // lane r16 owns row q=qw+r16 stats (copies equal across g)
        mlPart[((size_t)z * 32 + bh) * T_ + qw + r16] = make_float2(mS[sd], lS[sd]);
      #pragma unroll
      for (int j = 0; j < 4; ++j) {
        const int tq = qw + g * 4 + j;
        #pragma unroll
        for (int nf = 0; nf < 4; ++nf) {
          const int d = nf * 16 + r16;
          oPart[(((size_t)z * 32 + bh) * T_ + tq) * HD_ + d] = (__bf16)o[sd][nf][j];
        }
      }
    }
  }
#undef ASTAGE
}

// ---- combine 2 KV-split partials -> Y[b][t][h][d] bf16 ----
__global__ __launch_bounds__(256) void attn_combine_kernel(const __bf16* __restrict__ oPart,
                                                           const float2* __restrict__ mlPart,
                                                           __bf16* __restrict__ Y) {
  const int idx = blockIdx.x * 256 + threadIdx.x;  // 32*T*8 total (8 bf16 each)
  const int d8 = idx & 7;
  const int q = (idx >> 3) & (T_ - 1);
  const int bh = idx >> 14;
  const float2 ml0 = mlPart[(size_t)bh * T_ + q];
  const float2 ml1 = mlPart[((size_t)32 + bh) * T_ + q];
  const float M = fmaxf(ml0.x, ml1.x);
  float w0 = exp2f(ml0.x - M), w1 = exp2f(ml1.x - M);
  const float inv = 1.0f / (w0 * ml0.y + w1 * ml1.y);
  w0 *= inv; w1 *= inv;
  const bf16x8 o0 = *(const bf16x8*)&oPart[((size_t)bh * T_ + q) * HD_ + d8 * 8];
  const bf16x8 o1 = *(const bf16x8*)&oPart[(((size_t)32 + bh) * T_ + q) * HD_ + d8 * 8];
  const int b = bh >> 4, h = bh & 15;
  bf16x8 y;
  #pragma unroll
  for (int j = 0; j < 8; ++j)
    y[j] = (__bf16)(w0 * (float)o0[j] + w1 * (float)o1[j]);
  *(bf16x8*)&Y[(((size_t)b * T_ + q) * NH_ + h) * HD_ + d8 * 8] = y;
}

extern "C" void kernel_launch(void* const* d_in, const int* in_sizes, int n_in,
                              void* d_out, int out_size, void* d_ws, size_t ws_size,
                              hipStream_t stream) {
  const float* x = (const float*)d_in[0];
  const float* Wqkv = (const float*)d_in[1];
  const float* Wproj = (const float*)d_in[2];
  float* out = (float*)d_out;

  char* ws = (char*)d_ws;
  size_t off = 0;
  auto alloc = [&](size_t bytes) {
    char* p = ws + off;
    off += (bytes + 255) & ~(size_t)255;
    return p;
  };
  __bf16* xb     = (__bf16*)alloc((size_t)M_ * C_ * 2);          // 8 MB
  __bf16* wqkvT  = (__bf16*)alloc((size_t)NQKV_ * C_ * 2);       // 3 MB
  __bf16* wprojT = (__bf16*)alloc((size_t)C_ * C_ * 2);          // 2 MB
  float*  cosT   = (float*)alloc((size_t)T_ * 32 * 4);
  float*  sinT   = (float*)alloc((size_t)T_ * 32 * 4);
  float*  qkv    = (float*)alloc((size_t)M_ * NQKV_ * 4);        // 25 MB
  __bf16* Qb     = (__bf16*)alloc((size_t)B_ * NH_ * T_ * HD_ * 2);
  __bf16* Kb     = (__bf16*)alloc((size_t)B_ * NKV_ * T_ * HD_ * 2);
  __bf16* Vt     = (__bf16*)alloc((size_t)B_ * NKV_ * T_ * HD_ * 2);
  __bf16* Yb     = (__bf16*)alloc((size_t)M_ * C_ * 2);          // 8 MB
  // KV-split partials (only touched if ws_size allows the split path)
  __bf16* oPart  = (__bf16*)alloc((size_t)2 * 32 * T_ * HD_ * 2);   // 16.8 MB
  float2* mlPart = (float2*)alloc((size_t)2 * 32 * T_ * 8);         // 1 MB
  const bool use_split = ws_size >= off;

  hipLaunchKernelGGL(cast_x_kernel, dim3(M_ * C_ / 4 / 256), dim3(256), 0, stream, x, xb);
  hipLaunchKernelGGL(transpose_cast_kernel, dim3(NQKV_ / 64, C_ / 64), dim3(256), 0, stream,
                     Wqkv, wqkvT, C_, NQKV_);
  hipLaunchKernelGGL(transpose_cast_kernel, dim3(C_ / 64, C_ / 64), dim3(256), 0, stream,
                     Wproj, wprojT, C_, C_);
  hipLaunchKernelGGL(rope_table_kernel, dim3(T_ * 32 / 256), dim3(256), 0, stream, cosT, sinT);
  hipLaunchKernelGGL(gemm_tn_kernel, dim3(NQKV_ / 128, M_ / 128), dim3(256), 0, stream,
                     xb, wqkvT, qkv, NQKV_, C_);
  hipLaunchKernelGGL(rope_qk_kernel, dim3(M_ * (NH_ + NKV_) * 32 / 256), dim3(256), 0, stream,
                     qkv, cosT, sinT, Qb, Kb);
  hipLaunchKernelGGL(v_transpose_kernel, dim3(B_ * NKV_ * (T_ / 64)), dim3(256), 0, stream,
                     qkv, Vt);
  if (use_split) {
    hipLaunchKernelGGL(HIP_KERNEL_NAME(attn_kernel<2>), dim3(16 * B_ * NH_, 2), dim3(256), 0,
                       stream, Qb, Kb, Vt, Yb, oPart, mlPart);
    hipLaunchKernelGGL(attn_combine_kernel, dim3(32 * T_ * 8 / 256), dim3(256), 0, stream,
                       oPart, mlPart, Yb);
  } else {
    hipLaunchKernelGGL(HIP_KERNEL_NAME(attn_kernel<1>), dim3(16 * B_ * NH_), dim3(256), 0,
                       stream, Qb, Kb, Vt, Yb, oPart, mlPart);
  }
  hipLaunchKernelGGL(gemm_tn_kernel, dim3(C_ / 128, M_ / 128), dim3(256), 0, stream,
                     Yb, wprojT, out, C_, C_);
}

// Round 9
// 113.151 us; speedup vs baseline: 1.1596x; 1.1596x over previous
//
#include <hip/hip_runtime.h>
#include <hip/hip_bf16.h>

#define B_ 2
#define T_ 2048
#define C_ 1024
#define NH_ 16
#define NKV_ 4
#define HD_ 64
#define NQKV_ 1536           // (NH + 2*NKV) * HD
#define M_ 4096              // B_ * T_

typedef __attribute__((ext_vector_type(8))) __bf16 bf16x8;
typedef __attribute__((ext_vector_type(4))) __bf16 bf16x4;
typedef __attribute__((ext_vector_type(2))) __bf16 bf16x2;
typedef __attribute__((ext_vector_type(4))) float f32x4;
typedef __attribute__((ext_vector_type(4))) unsigned int u32x4;

#define GLOAD_LDS16(gptr, lptr)                                                        \
  __builtin_amdgcn_global_load_lds(                                                    \
      (const __attribute__((address_space(1))) unsigned int*)(gptr),                   \
      (__attribute__((address_space(3))) unsigned int*)(lptr), 16, 0, 0)

// ---------------- cast x (fp32 -> bf16), 4 elems/thread ----------------
__global__ __launch_bounds__(256) void cast_x_kernel(const float* __restrict__ in,
                                                     __bf16* __restrict__ out) {
  const int i = blockIdx.x * 256 + threadIdx.x;
  const float4 v = ((const float4*)in)[i];
  bf16x4 o;
  o.x = (__bf16)v.x; o.y = (__bf16)v.y; o.z = (__bf16)v.z; o.w = (__bf16)v.w;
  ((bf16x4*)out)[i] = o;
}

// ---------- transpose + cast: in [K][N] fp32 -> out [N][K] bf16 ----------
__global__ __launch_bounds__(256) void transpose_cast_kernel(const float* __restrict__ in,
                                                             __bf16* __restrict__ out,
                                                             int K, int N) {
  __shared__ __bf16 tile[64][72];  // [n_local][k_local], padded
  const int n0 = blockIdx.x * 64, k0 = blockIdx.y * 64;
  const int tid = threadIdx.x;
  const int tr = tid >> 4, tc4 = (tid & 15) << 2;
  #pragma unroll
  for (int p = 0; p < 4; ++p) {
    const int k = k0 + p * 16 + tr;
    const float4 v = *(const float4*)&in[(size_t)k * N + n0 + tc4];
    tile[tc4 + 0][p * 16 + tr] = (__bf16)v.x;
    tile[tc4 + 1][p * 16 + tr] = (__bf16)v.y;
    tile[tc4 + 2][p * 16 + tr] = (__bf16)v.z;
    tile[tc4 + 3][p * 16 + tr] = (__bf16)v.w;
  }
  __syncthreads();
  #pragma unroll
  for (int p = 0; p < 4; ++p) {
    const int n = n0 + p * 16 + tr;
    bf16x4 o;
    o.x = tile[p * 16 + tr][tc4 + 0];
    o.y = tile[p * 16 + tr][tc4 + 1];
    o.z = tile[p * 16 + tr][tc4 + 2];
    o.w = tile[p * 16 + tr][tc4 + 3];
    *(bf16x4*)&out[(size_t)n * K + k0 + tc4] = o;
  }
}

// ---------------- RoPE cos/sin tables [T][32] fp32 ----------------
__global__ __launch_bounds__(256) void rope_table_kernel(float* __restrict__ cosT,
                                                         float* __restrict__ sinT) {
  const int idx = blockIdx.x * 256 + threadIdx.x;  // T*32 total
  const int t = idx >> 5, i = idx & 31;
  const float inv = powf(10000.0f, -(float)i * (1.0f / 32.0f));
  const float ang = (float)t * inv;
  cosT[idx] = cosf(ang);
  sinT[idx] = sinf(ang);
}

// ------- bf16 TN GEMM: A[M][K] * Bt[N][K]^T -> C[M][N] (OutT) -------
// 128x64 tile, BK=64, 4 waves (2x2, each 64x32 out). Double-buffered
// global_load_lds (w=16): stage(t+1) issues BEFORE compute(t); vmcnt(0)+
// barrier once per tile. Pre-swizzled SOURCE + linear LDS dest (rule 21).
// BN=64 doubles the grid vs 128x128 (GEMM1 768 / GEMM2 512 blocks) to fix
// grid starvation; LDS 48KB -> 3 blocks/CU.
template <typename OutT>
__global__ __launch_bounds__(256) void gemm_tn_kernel(const __bf16* __restrict__ A,
                                                      const __bf16* __restrict__ Bt,
                                                      OutT* __restrict__ C, int N, int K) {
  __shared__ __align__(16) __bf16 lA[2][128 * 64];
  __shared__ __align__(16) __bf16 lB[2][64 * 64];
  const int tid = threadIdx.x;
  const int lane = tid & 63;
  const int wave = tid >> 6;
  const int wr = wave >> 1, wc = wave & 1;
  const int m0 = blockIdx.y * 128, n0 = blockIdx.x * 64;
  const int srow = tid >> 3, kc = tid & 7;  // staging: 8 threads/row, 16B chunks
  const int r16 = lane & 15, g = lane >> 4;
  f32x4 acc[4][2] = {};
  const int nt = K >> 6;

#define GSTAGE(buf, k0)                                                                   \
  {                                                                                       \
    _Pragma("unroll")                                                                     \
    for (int p = 0; p < 4; ++p) {                                                         \
      const int row = p * 32 + srow;                                                      \
      const int sw = (kc ^ (row & 7)) * 8;                                                \
      GLOAD_LDS16(&A[(size_t)(m0 + row) * K + (k0) + sw], &lA[buf][row * 64 + kc * 8]);   \
    }                                                                                     \
    _Pragma("unroll")                                                                     \
    for (int p = 0; p < 2; ++p) {                                                         \
      const int row = p * 32 + srow;                                                      \
      const int sw = (kc ^ (row & 7)) * 8;                                                \
      GLOAD_LDS16(&Bt[(size_t)(n0 + row) * K + (k0) + sw], &lB[buf][row * 64 + kc * 8]);  \
    }                                                                                     \
  }

  GSTAGE(0, 0);
  asm volatile("s_waitcnt vmcnt(0)" ::: "memory");
  __syncthreads();
  int cur = 0;
  for (int t = 0; t < nt; ++t) {
    if (t + 1 < nt) GSTAGE(cur ^ 1, (t + 1) << 6);   // loads fly under compute
    #pragma unroll
    for (int ks = 0; ks < 64; ks += 32) {
      bf16x8 af[4], bfr[2];
      const int kch = (ks >> 3) + g;
      #pragma unroll
      for (int mi = 0; mi < 4; ++mi) {
        const int row = wr * 64 + mi * 16 + r16;
        af[mi] = *(const bf16x8*)&lA[cur][row * 64 + (kch ^ (row & 7)) * 8];
      }
      #pragma unroll
      for (int ni = 0; ni < 2; ++ni) {
        const int row = wc * 32 + ni * 16 + r16;
        bfr[ni] = *(const bf16x8*)&lB[cur][row * 64 + (kch ^ (row & 7)) * 8];
      }
      #pragma unroll
      for (int mi = 0; mi < 4; ++mi)
        #pragma unroll
        for (int ni = 0; ni < 2; ++ni)
          acc[mi][ni] = __builtin_amdgcn_mfma_f32_16x16x32_bf16(af[mi], bfr[ni], acc[mi][ni], 0, 0, 0);
    }
    asm volatile("s_waitcnt vmcnt(0)" ::: "memory");  // next-tile loads landed
    __syncthreads();
    cur ^= 1;
  }
  // epilogue: D layout col=lane&15, row=(lane>>4)*4+j
  #pragma unroll
  for (int mi = 0; mi < 4; ++mi) {
    const int r0 = m0 + wr * 64 + mi * 16 + g * 4;
    #pragma unroll
    for (int ni = 0; ni < 2; ++ni) {
      const int c = n0 + wc * 32 + ni * 16 + r16;
      #pragma unroll
      for (int j = 0; j < 4; ++j)
        C[(size_t)(r0 + j) * N + c] = (OutT)acc[mi][ni][j];
    }
  }
#undef GSTAGE
}

// ---- RoPE on q,k (from bf16 qkv) -> Q[b][h][t][d], K[b][kvh][t][d] bf16 ----
// Q is additionally pre-scaled by 1/8 * log2(e) (softmax runs in exp2 domain).
__global__ __launch_bounds__(256) void rope_qk_kernel(const __bf16* __restrict__ qkv,
                                                      const float* __restrict__ cosT,
                                                      const float* __restrict__ sinT,
                                                      __bf16* __restrict__ Q,
                                                      __bf16* __restrict__ Kb) {
  const int idx = blockIdx.x * 256 + threadIdx.x;  // M_*(NH+NKV)*32 total
  const int i = idx & 31;
  const int rest = idx >> 5;
  const int head = rest % (NH_ + NKV_);
  const int row = rest / (NH_ + NKV_);
  const int b = row >> 11, t = row & 2047;
  const float c = cosT[t * 32 + i], s = sinT[t * 32 + i];
  if (head < NH_) {
    const bf16x2 pv = *(const bf16x2*)&qkv[(size_t)row * NQKV_ + head * HD_ + 2 * i];
    const float p0 = (float)pv.x, p1 = (float)pv.y;
    const float o1 = p0 * c - p1 * s;
    const float o2 = p0 * s + p1 * c;
    __bf16* q = &Q[(((size_t)b * NH_ + head) * T_ + t) * HD_ + 2 * i];
    const float qs = 0.125f * 1.44269504f;
    q[0] = (__bf16)(o1 * qs); q[1] = (__bf16)(o2 * qs);
  } else {
    const int kh = head - NH_;
    const bf16x2 pv = *(const bf16x2*)&qkv[(size_t)row * NQKV_ + NH_ * HD_ + kh * HD_ + 2 * i];
    const float p0 = (float)pv.x, p1 = (float)pv.y;
    const float o1 = p0 * c - p1 * s;
    const float o2 = p0 * s + p1 * c;
    __bf16* k = &Kb[(((size_t)b * NKV_ + kh) * T_ + t) * HD_ + 2 * i];
    k[0] = (__bf16)o1; k[1] = (__bf16)o2;
  }
}

// ---- V transpose: bf16 qkv v-part -> Vt[b][kvh][d][t] bf16 (LDS tiled) ----
__global__ __launch_bounds__(256) void v_transpose_kernel(const __bf16* __restrict__ qkv,
                                                          __bf16* __restrict__ Vt) {
  __shared__ __bf16 tile[64][72];  // [d][t_local], padded
  const int blk = blockIdx.x;      // B*NKV*(T/64)
  const int t0 = (blk & 31) * 64;
  const int kvh = (blk >> 5) & 3;
  const int b = blk >> 7;
  const int tid = threadIdx.x;
  const int tr = tid >> 4, c4 = (tid & 15) << 2;
  #pragma unroll
  for (int p = 0; p < 4; ++p) {
    const int t = t0 + p * 16 + tr;
    const bf16x4 v = *(const bf16x4*)&qkv[(size_t)(b * T_ + t) * NQKV_ + (NH_ + NKV_) * HD_ + kvh * HD_ + c4];
    tile[c4 + 0][p * 16 + tr] = v.x;
    tile[c4 + 1][p * 16 + tr] = v.y;
    tile[c4 + 2][p * 16 + tr] = v.z;
    tile[c4 + 3][p * 16 + tr] = v.w;
  }
  __syncthreads();
  #pragma unroll
  for (int p = 0; p < 4; ++p) {
    const int d = p * 16 + tr;
    bf16x4 o;
    o.x = tile[d][c4 + 0]; o.y = tile[d][c4 + 1];
    o.z = tile[d][c4 + 2]; o.w = tile[d][c4 + 3];
    *(bf16x4*)&Vt[(((size_t)b * NKV_ + kvh) * HD_ + d) * T_ + t0 + c4] = o;
  }
}

// ---- flash attention, triangle-paired, swapped-QK softmax, K/V LDS dbuf ----
// Block pair index i handles q-tiles {i, 31-i} in one shared KV sweep (33
// tile-activations/block -> uniform). K/V double-buffered in LDS, staged by
// global_load_lds (pre-swizzled source + linear dest); ONE barrier per tile.
// Swapped QK^T (mfma(K,Q)) puts full row stats in-lane. No setprio (T5 null
// in lockstep structures, m190); no sched_barrier (compiler-tracked DS deps).
__global__ __launch_bounds__(256) void attn_kernel(const __bf16* __restrict__ Q,
                                                   const __bf16* __restrict__ Kb,
                                                   const __bf16* __restrict__ Vt,
                                                   __bf16* __restrict__ Y) {
  __shared__ __align__(16) __bf16 lK[2][64 * 64];   // [kv][d], swizzled
  __shared__ __align__(16) __bf16 lV[2][64 * 64];   // [d][kv], swizzled
  __shared__ __align__(16) __bf16 pP[4][16 * 64];   // per-wave [q][kv], swizzled
  const int tid = threadIdx.x;
  const int lane = tid & 63, wave = tid >> 6;
  const int r16 = lane & 15, g = lane >> 4;
  // bijective XCD swizzle (T1): 512 blocks, 8 XCDs -> 64 contiguous logical
  // ids per XCD so blocks sharing (b,kvh)'s K/V co-locate in one L2.
  const int logical = (blockIdx.x & 7) * 64 + (blockIdx.x >> 3);
  const int i = logical & 15;        // pair index: q-tiles {i, 31-i}
  const int bh = logical >> 4;
  const int b = bh >> 4, h = bh & 15;
  const int kvh = h >> 2;  // GQA rep = 4
  const __bf16* Qp = Q + ((size_t)b * NH_ + h) * T_ * HD_;
  const __bf16* Kp = Kb + ((size_t)b * NKV_ + kvh) * T_ * HD_;
  const __bf16* Vp = Vt + ((size_t)b * NKV_ + kvh) * HD_ * T_;
  const int qtile[2] = { i, 31 - i };
  const int srow = tid >> 3, kc = tid & 7;          // staging: 8x16B chunks/row

#define ASTAGE(buf, kv0_)                                                                  \
  {                                                                                        \
    _Pragma("unroll")                                                                      \
    for (int p = 0; p < 2; ++p) {                                                          \
      const int row = p * 32 + srow;                                                       \
      const int sw = (kc ^ (row & 7)) * 8;                                                 \
      GLOAD_LDS16(&Kp[(size_t)((kv0_) + row) * HD_ + sw], &lK[buf][row * 64 + kc * 8]);    \
      GLOAD_LDS16(&Vp[(size_t)row * T_ + (kv0_) + sw], &lV[buf][row * 64 + kc * 8]);       \
    }                                                                                      \
  }

  // Q fragments; pre-scaled by 1/8*log2e in rope_qk. B-operand of swapped QK.
  bf16x8 qf[2][2];
  #pragma unroll
  for (int sd = 0; sd < 2; ++sd)
    #pragma unroll
    for (int c = 0; c < 2; ++c)
      qf[sd][c] = *(const bf16x8*)&Qp[(size_t)(qtile[sd] * 64 + wave * 16 + r16) * HD_ + (c * 4 + g) * 8];

  f32x4 o[2][4] = {};
  float mS[2], lS[2];
  #pragma unroll
  for (int sd = 0; sd < 2; ++sd) { mS[sd] = -__builtin_inff(); lS[sd] = 0.0f; }

  // softmax + P-write for one side (lane owns full row q=qw+r16 of S^T)
  auto sm_side = [&](f32x4 (&s)[4], int sd) {
    // in-lane 16->1 max, max3-shaped triples (T17)
    float t0 = fmaxf(fmaxf(s[0][0], s[0][1]), s[0][2]);
    float t1 = fmaxf(fmaxf(s[0][3], s[1][0]), s[1][1]);
    float t2 = fmaxf(fmaxf(s[1][2], s[1][3]), s[2][0]);
    float t3 = fmaxf(fmaxf(s[2][1], s[2][2]), s[2][3]);
    float t4 = fmaxf(fmaxf(s[3][0], s[3][1]), s[3][2]);
    float pm = fmaxf(fmaxf(t0, t1), t2);
    pm = fmaxf(pm, fmaxf(t3, t4));
    pm = fmaxf(pm, s[3][3]);
    pm = fmaxf(pm, __shfl_xor(pm, 16));
    pm = fmaxf(pm, __shfl_xor(pm, 32));
    const bool upd = pm > mS[sd] + 8.0f;   // deferred-max (T13)
    const float nm = upd ? pm : mS[sd];
    const float sc = exp2f(mS[sd] - nm);   // ==1.0 exactly when !upd
    mS[sd] = nm;
    lS[sd] *= sc;
    if (__any(upd)) {  // redistribute sc from q=r16 layout to (g,j) layout
      #pragma unroll
      for (int j = 0; j < 4; ++j) {
        const float scj = __shfl(sc, g * 4 + j);
        #pragma unroll
        for (int nf = 0; nf < 4; ++nf) o[sd][nf][j] *= scj;
      }
    }
    // P = exp2(S-m): write each pb chunk ASAP (hides DS latency under the
    // remaining exp2s and the rs shfl chain), reduce rs after.
    float rs = 0.0f;
    #pragma unroll
    for (int ni = 0; ni < 4; ++ni) {
      bf16x4 pb;
      #pragma unroll
      for (int j = 0; j < 4; ++j) {
        const float pv = exp2f(s[ni][j] - mS[sd]);
        rs += pv;
        pb[j] = (__bf16)pv;
      }
      const int ch = 2 * ni + (g >> 1);    // row q=r16, kv-chunk, half g&1
      *(bf16x4*)&pP[wave][r16 * 64 + ((ch ^ (r16 & 7)) * 8) + (g & 1) * 4] = pb;
    }
    rs += __shfl_xor(rs, 16);
    rs += __shfl_xor(rs, 32);
    lS[sd] += rs;
  };

  const int ntiles = 32 - i;         // KV tiles needed by side B (q-tile 31-i)
  ASTAGE(0, 0);
  asm volatile("s_waitcnt vmcnt(0)" ::: "memory");
  __syncthreads();
  int cur = 0;

  for (int t = 0; t < ntiles; ++t) {
    const int kv0 = t << 6;
    if (t + 1 < ntiles) ASTAGE(cur ^ 1, kv0 + 64);  // next tile under compute

    #pragma unroll
    for (int sd = 0; sd < 2; ++sd) {
      if (sd == 0 && t > i) continue;       // side A inactive past its diagonal
      const int qw = qtile[sd] * 64 + wave * 16;

      // ---- QK^T swapped: s[ni][j] = S[kv0+ni*16+g*4+j][qw+r16] ----
      f32x4 s[4] = {};
      #pragma unroll
      for (int c = 0; c < 2; ++c) {
        bf16x8 kf[4];
        #pragma unroll
        for (int ni = 0; ni < 4; ++ni) {
          const int row = ni * 16 + r16;
          kf[ni] = *(const bf16x8*)&lK[cur][row * 64 + ((c * 4 + g) ^ (row & 7)) * 8];
        }
        #pragma unroll
        for (int ni = 0; ni < 4; ++ni)
          s[ni] = __builtin_amdgcn_mfma_f32_16x16x32_bf16(kf[ni], qf[sd][c], s[ni], 0, 0, 0);
      }

      // ---- causal mask (diagonal tile of this side only) ----
      if (t == ((sd == 0) ? i : (ntiles - 1))) {
        #pragma unroll
        for (int ni = 0; ni < 4; ++ni)
          #pragma unroll
          for (int j = 0; j < 4; ++j)
            if (kv0 + ni * 16 + g * 4 + j > qw + r16) s[ni][j] = -__builtin_inff();
      }

      sm_side(s, sd);
      asm volatile("s_waitcnt lgkmcnt(0)" ::: "memory");  // P writes drained

      // ---- PV: O += P * V^T, 8 MFMAs ----
      #pragma unroll
      for (int c = 0; c < 2; ++c) {
        const bf16x8 pf = *(const bf16x8*)&pP[wave][r16 * 64 + (((c * 4 + g) ^ (r16 & 7)) * 8)];
        #pragma unroll
        for (int nf = 0; nf < 4; ++nf) {
          const int row = nf * 16 + r16;
          const bf16x8 vf = *(const bf16x8*)&lV[cur][row * 64 + ((c * 4 + g) ^ (row & 7)) * 8];
          o[sd][nf] = __builtin_amdgcn_mfma_f32_16x16x32_bf16(pf, vf, o[sd][nf], 0, 0, 0);
        }
      }
    }

    asm volatile("s_waitcnt vmcnt(0)" ::: "memory");  // next-tile loads landed
    __syncthreads();
    cur ^= 1;
  }

  // ---- epilogue -> Y[b][t][h][d] bf16 (both sides); l via shfl ----
  #pragma unroll
  for (int sd = 0; sd < 2; ++sd) {
    const int qw = qtile[sd] * 64 + wave * 16;
    #pragma unroll
    for (int j = 0; j < 4; ++j) {
      const float lq = __shfl(lS[sd], g * 4 + j);
      const float inv = 1.0f / lq;
      const int tq = qw + g * 4 + j;
      #pragma unroll
      for (int nf = 0; nf < 4; ++nf) {
        const int d = nf * 16 + r16;
        Y[(((size_t)b * T_ + tq) * NH_ + h) * HD_ + d] = (__bf16)(o[sd][nf][j] * inv);
      }
    }
  }
#undef ASTAGE
}

extern "C" void kernel_launch(void* const* d_in, const int* in_sizes, int n_in,
                              void* d_out, int out_size, void* d_ws, size_t ws_size,
                              hipStream_t stream) {
  const float* x = (const float*)d_in[0];
  const float* Wqkv = (const float*)d_in[1];
  const float* Wproj = (const float*)d_in[2];
  float* out = (float*)d_out;

  char* ws = (char*)d_ws;
  size_t off = 0;
  auto alloc = [&](size_t bytes) {
    char* p = ws + off;
    off += (bytes + 255) & ~(size_t)255;
    return p;
  };
  __bf16* xb     = (__bf16*)alloc((size_t)M_ * C_ * 2);          // 8 MB
  __bf16* wqkvT  = (__bf16*)alloc((size_t)NQKV_ * C_ * 2);       // 3 MB
  __bf16* wprojT = (__bf16*)alloc((size_t)C_ * C_ * 2);          // 2 MB
  float*  cosT   = (float*)alloc((size_t)T_ * 32 * 4);
  float*  sinT   = (float*)alloc((size_t)T_ * 32 * 4);
  __bf16* qkv    = (__bf16*)alloc((size_t)M_ * NQKV_ * 2);       // 12.6 MB (bf16)
  __bf16* Qb     = (__bf16*)alloc((size_t)B_ * NH_ * T_ * HD_ * 2);
  __bf16* Kb     = (__bf16*)alloc((size_t)B_ * NKV_ * T_ * HD_ * 2);
  __bf16* Vt     = (__bf16*)alloc((size_t)B_ * NKV_ * T_ * HD_ * 2);
  __bf16* Yb     = (__bf16*)alloc((size_t)M_ * C_ * 2);          // 8 MB

  hipLaunchKernelGGL(cast_x_kernel, dim3(M_ * C_ / 4 / 256), dim3(256), 0, stream, x, xb);
  hipLaunchKernelGGL(transpose_cast_kernel, dim3(NQKV_ / 64, C_ / 64), dim3(256), 0, stream,
                     Wqkv, wqkvT, C_, NQKV_);
  hipLaunchKernelGGL(transpose_cast_kernel, dim3(C_ / 64, C_ / 64), dim3(256), 0, stream,
                     Wproj, wprojT, C_, C_);
  hipLaunchKernelGGL(rope_table_kernel, dim3(T_ * 32 / 256), dim3(256), 0, stream, cosT, sinT);
  hipLaunchKernelGGL(HIP_KERNEL_NAME(gemm_tn_kernel<__bf16>), dim3(NQKV_ / 64, M_ / 128),
                     dim3(256), 0, stream, xb, wqkvT, qkv, NQKV_, C_);
  hipLaunchKernelGGL(rope_qk_kernel, dim3(M_ * (NH_ + NKV_) * 32 / 256), dim3(256), 0, stream,
                     qkv, cosT, sinT, Qb, Kb);
  hipLaunchKernelGGL(v_transpose_kernel, dim3(B_ * NKV_ * (T_ / 64)), dim3(256), 0, stream,
                     qkv, Vt);
  hipLaunchKernelGGL(attn_kernel, dim3(16 * B_ * NH_), dim3(256), 0, stream, Qb, Kb, Vt, Yb);
  hipLaunchKernelGGL(HIP_KERNEL_NAME(gemm_tn_kernel<float>), dim3(C_ / 64, M_ / 128),
                     dim3(256), 0, stream, Yb, wprojT, out, C_, C_);
}

// Round 10
// 105.321 us; speedup vs baseline: 1.2458x; 1.0743x over previous
//
#include <hip/hip_runtime.h>
#include <hip/hip_bf16.h>

#define B_ 2
#define T_ 2048
#define C_ 1024
#define NH_ 16
#define NKV_ 4
#define HD_ 64
#define NQKV_ 1536           // (NH + 2*NKV) * HD
#define M_ 4096              // B_ * T_

typedef __attribute__((ext_vector_type(8))) __bf16 bf16x8;
typedef __attribute__((ext_vector_type(4))) __bf16 bf16x4;
typedef __attribute__((ext_vector_type(2))) __bf16 bf16x2;
typedef __attribute__((ext_vector_type(4))) float f32x4;
typedef __attribute__((ext_vector_type(4))) unsigned int u32x4;

// raw v_exp_f32 (D = 2^S0): 1 instruction, ~1 ulp — plenty for bf16 outputs.
// exp2f without fast-math lowers to a denormal-safe multi-instruction expansion.
__device__ __forceinline__ float fast_exp2(float x) { return __builtin_amdgcn_exp2f(x); }

#define GLOAD_LDS16(gptr, lptr)                                                        \
  __builtin_amdgcn_global_load_lds(                                                    \
      (const __attribute__((address_space(1))) unsigned int*)(gptr),                   \
      (__attribute__((address_space(3))) unsigned int*)(lptr), 16, 0, 0)

// ---------------- cast x (fp32 -> bf16), 4 elems/thread ----------------
__global__ __launch_bounds__(256) void cast_x_kernel(const float* __restrict__ in,
                                                     __bf16* __restrict__ out) {
  const int i = blockIdx.x * 256 + threadIdx.x;
  const float4 v = ((const float4*)in)[i];
  bf16x4 o;
  o.x = (__bf16)v.x; o.y = (__bf16)v.y; o.z = (__bf16)v.z; o.w = (__bf16)v.w;
  ((bf16x4*)out)[i] = o;
}

// ---------- transpose + cast: in [K][N] fp32 -> out [N][K] bf16 ----------
__global__ __launch_bounds__(256) void transpose_cast_kernel(const float* __restrict__ in,
                                                             __bf16* __restrict__ out,
                                                             int K, int N) {
  __shared__ __bf16 tile[64][72];  // [n_local][k_local], padded
  const int n0 = blockIdx.x * 64, k0 = blockIdx.y * 64;
  const int tid = threadIdx.x;
  const int tr = tid >> 4, tc4 = (tid & 15) << 2;
  #pragma unroll
  for (int p = 0; p < 4; ++p) {
    const int k = k0 + p * 16 + tr;
    const float4 v = *(const float4*)&in[(size_t)k * N + n0 + tc4];
    tile[tc4 + 0][p * 16 + tr] = (__bf16)v.x;
    tile[tc4 + 1][p * 16 + tr] = (__bf16)v.y;
    tile[tc4 + 2][p * 16 + tr] = (__bf16)v.z;
    tile[tc4 + 3][p * 16 + tr] = (__bf16)v.w;
  }
  __syncthreads();
  #pragma unroll
  for (int p = 0; p < 4; ++p) {
    const int n = n0 + p * 16 + tr;
    bf16x4 o;
    o.x = tile[p * 16 + tr][tc4 + 0];
    o.y = tile[p * 16 + tr][tc4 + 1];
    o.z = tile[p * 16 + tr][tc4 + 2];
    o.w = tile[p * 16 + tr][tc4 + 3];
    *(bf16x4*)&out[(size_t)n * K + k0 + tc4] = o;
  }
}

// ---------------- RoPE cos/sin tables [T][32] fp32 ----------------
__global__ __launch_bounds__(256) void rope_table_kernel(float* __restrict__ cosT,
                                                         float* __restrict__ sinT) {
  const int idx = blockIdx.x * 256 + threadIdx.x;  // T*32 total
  const int t = idx >> 5, i = idx & 31;
  const float inv = powf(10000.0f, -(float)i * (1.0f / 32.0f));
  const float ang = (float)t * inv;
  cosT[idx] = cosf(ang);
  sinT[idx] = sinf(ang);
}

// ------- bf16 TN GEMM: A[M][K] * Bt[N][K]^T -> C[M][N] (OutT) -------
// 128x64 tile, BK=64, 4 waves (2x2, each 64x32 out). Double-buffered
// global_load_lds (w=16): stage(t+1) issues BEFORE compute(t); vmcnt(0)+
// barrier once per tile. Pre-swizzled SOURCE + linear LDS dest (rule 21).
template <typename OutT>
__global__ __launch_bounds__(256) void gemm_tn_kernel(const __bf16* __restrict__ A,
                                                      const __bf16* __restrict__ Bt,
                                                      OutT* __restrict__ C, int N, int K) {
  __shared__ __align__(16) __bf16 lA[2][128 * 64];
  __shared__ __align__(16) __bf16 lB[2][64 * 64];
  const int tid = threadIdx.x;
  const int lane = tid & 63;
  const int wave = tid >> 6;
  const int wr = wave >> 1, wc = wave & 1;
  const int m0 = blockIdx.y * 128, n0 = blockIdx.x * 64;
  const int srow = tid >> 3, kc = tid & 7;  // staging: 8 threads/row, 16B chunks
  const int r16 = lane & 15, g = lane >> 4;
  f32x4 acc[4][2] = {};
  const int nt = K >> 6;

#define GSTAGE(buf, k0)                                                                   \
  {                                                                                       \
    _Pragma("unroll")                                                                     \
    for (int p = 0; p < 4; ++p) {                                                         \
      const int row = p * 32 + srow;                                                      \
      const int sw = (kc ^ (row & 7)) * 8;                                                \
      GLOAD_LDS16(&A[(size_t)(m0 + row) * K + (k0) + sw], &lA[buf][row * 64 + kc * 8]);   \
    }                                                                                     \
    _Pragma("unroll")                                                                     \
    for (int p = 0; p < 2; ++p) {                                                         \
      const int row = p * 32 + srow;                                                      \
      const int sw = (kc ^ (row & 7)) * 8;                                                \
      GLOAD_LDS16(&Bt[(size_t)(n0 + row) * K + (k0) + sw], &lB[buf][row * 64 + kc * 8]);  \
    }                                                                                     \
  }

  GSTAGE(0, 0);
  asm volatile("s_waitcnt vmcnt(0)" ::: "memory");
  __syncthreads();
  int cur = 0;
  for (int t = 0; t < nt; ++t) {
    if (t + 1 < nt) GSTAGE(cur ^ 1, (t + 1) << 6);   // loads fly under compute
    #pragma unroll
    for (int ks = 0; ks < 64; ks += 32) {
      bf16x8 af[4], bfr[2];
      const int kch = (ks >> 3) + g;
      #pragma unroll
      for (int mi = 0; mi < 4; ++mi) {
        const int row = wr * 64 + mi * 16 + r16;
        af[mi] = *(const bf16x8*)&lA[cur][row * 64 + (kch ^ (row & 7)) * 8];
      }
      #pragma unroll
      for (int ni = 0; ni < 2; ++ni) {
        const int row = wc * 32 + ni * 16 + r16;
        bfr[ni] = *(const bf16x8*)&lB[cur][row * 64 + (kch ^ (row & 7)) * 8];
      }
      #pragma unroll
      for (int mi = 0; mi < 4; ++mi)
        #pragma unroll
        for (int ni = 0; ni < 2; ++ni)
          acc[mi][ni] = __builtin_amdgcn_mfma_f32_16x16x32_bf16(af[mi], bfr[ni], acc[mi][ni], 0, 0, 0);
    }
    asm volatile("s_waitcnt vmcnt(0)" ::: "memory");  // next-tile loads landed
    __syncthreads();
    cur ^= 1;
  }
  // epilogue: D layout col=lane&15, row=(lane>>4)*4+j
  #pragma unroll
  for (int mi = 0; mi < 4; ++mi) {
    const int r0 = m0 + wr * 64 + mi * 16 + g * 4;
    #pragma unroll
    for (int ni = 0; ni < 2; ++ni) {
      const int c = n0 + wc * 32 + ni * 16 + r16;
      #pragma unroll
      for (int j = 0; j < 4; ++j)
        C[(size_t)(r0 + j) * N + c] = (OutT)acc[mi][ni][j];
    }
  }
#undef GSTAGE
}

// ---- RoPE on q,k (bf16 qkv) -> Q[b][h][t][d], K[b][kvh][t][d] bf16 ----
// 8 elems (4 rotation pairs) per thread: bf16x8 load, float4 cos/sin, one
// 16B store (G13). q/k source regions are contiguous: offset = head*HD works
// for both. Q additionally pre-scaled by 1/8*log2(e) (exp2-domain softmax).
__global__ __launch_bounds__(256) void rope_qk_kernel(const __bf16* __restrict__ qkv,
                                                      const float* __restrict__ cosT,
                                                      const float* __restrict__ sinT,
                                                      __bf16* __restrict__ Q,
                                                      __bf16* __restrict__ Kb) {
  const int idx = blockIdx.x * 256 + threadIdx.x;  // M_*(NH+NKV)*8 total
  const int i8 = idx & 7;
  const int rest = idx >> 3;
  const int head = rest % (NH_ + NKV_);
  const int row = rest / (NH_ + NKV_);
  const int b = row >> 11, t = row & 2047;
  const float4 cv = *(const float4*)&cosT[t * 32 + i8 * 4];
  const float4 sv = *(const float4*)&sinT[t * 32 + i8 * 4];
  const bf16x8 v = *(const bf16x8*)&qkv[(size_t)row * NQKV_ + head * HD_ + i8 * 8];
  const bool isq = head < NH_;
  const float qs = isq ? 0.125f * 1.44269504f : 1.0f;
  bf16x8 o;
  #pragma unroll
  for (int p = 0; p < 4; ++p) {
    const float x1 = (float)v[2 * p], x2 = (float)v[2 * p + 1];
    const float c = (&cv.x)[p], s = (&sv.x)[p];
    o[2 * p]     = (__bf16)((x1 * c - x2 * s) * qs);
    o[2 * p + 1] = (__bf16)((x1 * s + x2 * c) * qs);
  }
  __bf16* dst = isq ? &Q[(((size_t)b * NH_ + head) * T_ + t) * HD_ + i8 * 8]
                    : &Kb[(((size_t)b * NKV_ + (head - NH_)) * T_ + t) * HD_ + i8 * 8];
  *(bf16x8*)dst = o;
}

// ---- V transpose: bf16 qkv v-part -> Vt[b][kvh][d][t] bf16 (LDS tiled) ----
__global__ __launch_bounds__(256) void v_transpose_kernel(const __bf16* __restrict__ qkv,
                                                          __bf16* __restrict__ Vt) {
  __shared__ __bf16 tile[64][72];  // [d][t_local], padded
  const int blk = blockIdx.x;      // B*NKV*(T/64)
  const int t0 = (blk & 31) * 64;
  const int kvh = (blk >> 5) & 3;
  const int b = blk >> 7;
  const int tid = threadIdx.x;
  const int tr = tid >> 4, c4 = (tid & 15) << 2;
  #pragma unroll
  for (int p = 0; p < 4; ++p) {
    const int t = t0 + p * 16 + tr;
    const bf16x4 v = *(const bf16x4*)&qkv[(size_t)(b * T_ + t) * NQKV_ + (NH_ + NKV_) * HD_ + kvh * HD_ + c4];
    tile[c4 + 0][p * 16 + tr] = v.x;
    tile[c4 + 1][p * 16 + tr] = v.y;
    tile[c4 + 2][p * 16 + tr] = v.z;
    tile[c4 + 3][p * 16 + tr] = v.w;
  }
  __syncthreads();
  #pragma unroll
  for (int p = 0; p < 4; ++p) {
    const int d = p * 16 + tr;
    bf16x4 o;
    o.x = tile[d][c4 + 0]; o.y = tile[d][c4 + 1];
    o.z = tile[d][c4 + 2]; o.w = tile[d][c4 + 3];
    *(bf16x4*)&Vt[(((size_t)b * NKV_ + kvh) * HD_ + d) * T_ + t0 + c4] = o;
  }
}

// ---- flash attention, triangle-paired, swapped-QK softmax, K/V LDS dbuf ----
// Block pair index i handles q-tiles {i, 31-i} in one shared KV sweep (33
// tile-activations/block -> uniform). K/V double-buffered in LDS, staged by
// global_load_lds (pre-swizzled source + linear dest); ONE barrier per tile.
// Swapped QK^T (mfma(K,Q)) puts full row stats in-lane; exponentials are raw
// v_exp_f32 via __builtin_amdgcn_exp2f (exp2f lowers to a multi-instr
// denormal-safe expansion without fast-math — ~35% of the VALU budget).
__global__ __launch_bounds__(256) void attn_kernel(const __bf16* __restrict__ Q,
                                                   const __bf16* __restrict__ Kb,
                                                   const __bf16* __restrict__ Vt,
                                                   __bf16* __restrict__ Y) {
  __shared__ __align__(16) __bf16 lK[2][64 * 64];   // [kv][d], swizzled
  __shared__ __align__(16) __bf16 lV[2][64 * 64];   // [d][kv], swizzled
  __shared__ __align__(16) __bf16 pP[4][16 * 64];   // per-wave [q][kv], swizzled
  const int tid = threadIdx.x;
  const int lane = tid & 63, wave = tid >> 6;
  const int r16 = lane & 15, g = lane >> 4;
  // bijective XCD swizzle (T1): 512 blocks, 8 XCDs -> 64 contiguous logical
  // ids per XCD so blocks sharing (b,kvh)'s K/V co-locate in one L2.
  const int logical = (blockIdx.x & 7) * 64 + (blockIdx.x >> 3);
  const int i = logical & 15;        // pair index: q-tiles {i, 31-i}
  const int bh = logical >> 4;
  const int b = bh >> 4, h = bh & 15;
  const int kvh = h >> 2;  // GQA rep = 4
  const __bf16* Qp = Q + ((size_t)b * NH_ + h) * T_ * HD_;
  const __bf16* Kp = Kb + ((size_t)b * NKV_ + kvh) * T_ * HD_;
  const __bf16* Vp = Vt + ((size_t)b * NKV_ + kvh) * HD_ * T_;
  const int qtile[2] = { i, 31 - i };
  const int srow = tid >> 3, kc = tid & 7;          // staging: 8x16B chunks/row

#define ASTAGE(buf, kv0_)                                                                  \
  {                                                                                        \
    _Pragma("unroll")                                                                      \
    for (int p = 0; p < 2; ++p) {                                                          \
      const int row = p * 32 + srow;                                                       \
      const int sw = (kc ^ (row & 7)) * 8;                                                 \
      GLOAD_LDS16(&Kp[(size_t)((kv0_) + row) * HD_ + sw], &lK[buf][row * 64 + kc * 8]);    \
      GLOAD_LDS16(&Vp[(size_t)row * T_ + (kv0_) + sw], &lV[buf][row * 64 + kc * 8]);       \
    }                                                                                      \
  }

  // Q fragments; pre-scaled by 1/8*log2e in rope_qk. B-operand of swapped QK.
  bf16x8 qf[2][2];
  #pragma unroll
  for (int sd = 0; sd < 2; ++sd)
    #pragma unroll
    for (int c = 0; c < 2; ++c)
      qf[sd][c] = *(const bf16x8*)&Qp[(size_t)(qtile[sd] * 64 + wave * 16 + r16) * HD_ + (c * 4 + g) * 8];

  f32x4 o[2][4] = {};
  float mS[2], lS[2];
  #pragma unroll
  for (int sd = 0; sd < 2; ++sd) { mS[sd] = -__builtin_inff(); lS[sd] = 0.0f; }

  // softmax + P-write for one side (lane owns full row q=qw+r16 of S^T)
  auto sm_side = [&](f32x4 (&s)[4], int sd) {
    // in-lane 16->1 max, max3-shaped triples (T17)
    float t0 = fmaxf(fmaxf(s[0][0], s[0][1]), s[0][2]);
    float t1 = fmaxf(fmaxf(s[0][3], s[1][0]), s[1][1]);
    float t2 = fmaxf(fmaxf(s[1][2], s[1][3]), s[2][0]);
    float t3 = fmaxf(fmaxf(s[2][1], s[2][2]), s[2][3]);
    float t4 = fmaxf(fmaxf(s[3][0], s[3][1]), s[3][2]);
    float pm = fmaxf(fmaxf(t0, t1), t2);
    pm = fmaxf(pm, fmaxf(t3, t4));
    pm = fmaxf(pm, s[3][3]);
    pm = fmaxf(pm, __shfl_xor(pm, 16));
    pm = fmaxf(pm, __shfl_xor(pm, 32));
    const bool upd = pm > mS[sd] + 8.0f;   // deferred-max (T13)
    const float nm = upd ? pm : mS[sd];
    const float sc = fast_exp2(mS[sd] - nm);   // ==1.0 exactly when !upd
    mS[sd] = nm;
    lS[sd] *= sc;
    if (__any(upd)) {  // redistribute sc from q=r16 layout to (g,j) layout
      #pragma unroll
      for (int j = 0; j < 4; ++j) {
        const float scj = __shfl(sc, g * 4 + j);
        #pragma unroll
        for (int nf = 0; nf < 4; ++nf) o[sd][nf][j] *= scj;
      }
    }
    // P = exp2(S-m): write each pb chunk ASAP (hides DS latency under the
    // remaining exp2s and the rs shfl chain), reduce rs after.
    float rs = 0.0f;
    #pragma unroll
    for (int ni = 0; ni < 4; ++ni) {
      bf16x4 pb;
      #pragma unroll
      for (int j = 0; j < 4; ++j) {
        const float pv = fast_exp2(s[ni][j] - mS[sd]);
        rs += pv;
        pb[j] = (__bf16)pv;
      }
      const int ch = 2 * ni + (g >> 1);    // row q=r16, kv-chunk, half g&1
      *(bf16x4*)&pP[wave][r16 * 64 + ((ch ^ (r16 & 7)) * 8) + (g & 1) * 4] = pb;
    }
    rs += __shfl_xor(rs, 16);
    rs += __shfl_xor(rs, 32);
    lS[sd] += rs;
  };

  const int ntiles = 32 - i;         // KV tiles needed by side B (q-tile 31-i)
  ASTAGE(0, 0);
  asm volatile("s_waitcnt vmcnt(0)" ::: "memory");
  __syncthreads();
  int cur = 0;

  for (int t = 0; t < ntiles; ++t) {
    const int kv0 = t << 6;
    if (t + 1 < ntiles) ASTAGE(cur ^ 1, kv0 + 64);  // next tile under compute

    #pragma unroll
    for (int sd = 0; sd < 2; ++sd) {
      if (sd == 0 && t > i) continue;       // side A inactive past its diagonal
      const int qw = qtile[sd] * 64 + wave * 16;

      // ---- QK^T swapped: s[ni][j] = S[kv0+ni*16+g*4+j][qw+r16] ----
      f32x4 s[4] = {};
      #pragma unroll
      for (int c = 0; c < 2; ++c) {
        bf16x8 kf[4];
        #pragma unroll
        for (int ni = 0; ni < 4; ++ni) {
          const int row = ni * 16 + r16;
          kf[ni] = *(const bf16x8*)&lK[cur][row * 64 + ((c * 4 + g) ^ (row & 7)) * 8];
        }
        #pragma unroll
        for (int ni = 0; ni < 4; ++ni)
          s[ni] = __builtin_amdgcn_mfma_f32_16x16x32_bf16(kf[ni], qf[sd][c], s[ni], 0, 0, 0);
      }

      // ---- causal mask (diagonal tile of this side only) ----
      if (t == ((sd == 0) ? i : (ntiles - 1))) {
        #pragma unroll
        for (int ni = 0; ni < 4; ++ni)
          #pragma unroll
          for (int j = 0; j < 4; ++j)
            if (kv0 + ni * 16 + g * 4 + j > qw + r16) s[ni][j] = -__builtin_inff();
      }

      sm_side(s, sd);
      asm volatile("s_waitcnt lgkmcnt(0)" ::: "memory");  // P writes drained

      // ---- PV: O += P * V^T, 8 MFMAs ----
      #pragma unroll
      for (int c = 0; c < 2; ++c) {
        const bf16x8 pf = *(const bf16x8*)&pP[wave][r16 * 64 + (((c * 4 + g) ^ (r16 & 7)) * 8)];
        #pragma unroll
        for (int nf = 0; nf < 4; ++nf) {
          const int row = nf * 16 + r16;
          const bf16x8 vf = *(const bf16x8*)&lV[cur][row * 64 + ((c * 4 + g) ^ (row & 7)) * 8];
          o[sd][nf] = __builtin_amdgcn_mfma_f32_16x16x32_bf16(pf, vf, o[sd][nf], 0, 0, 0);
        }
      }
    }

    asm volatile("s_waitcnt vmcnt(0)" ::: "memory");  // next-tile loads landed
    __syncthreads();
    cur ^= 1;
  }

  // ---- epilogue -> Y[b][t][h][d] bf16 (both sides); l via shfl ----
  #pragma unroll
  for (int sd = 0; sd < 2; ++sd) {
    const int qw = qtile[sd] * 64 + wave * 16;
    #pragma unroll
    for (int j = 0; j < 4; ++j) {
      const float lq = __shfl(lS[sd], g * 4 + j);
      const float inv = 1.0f / lq;
      const int tq = qw + g * 4 + j;
      #pragma unroll
      for (int nf = 0; nf < 4; ++nf) {
        const int d = nf * 16 + r16;
        Y[(((size_t)b * T_ + tq) * NH_ + h) * HD_ + d] = (__bf16)(o[sd][nf][j] * inv);
      }
    }
  }
#undef ASTAGE
}

extern "C" void kernel_launch(void* const* d_in, const int* in_sizes, int n_in,
                              void* d_out, int out_size, void* d_ws, size_t ws_size,
                              hipStream_t stream) {
  const float* x = (const float*)d_in[0];
  const float* Wqkv = (const float*)d_in[1];
  const float* Wproj = (const float*)d_in[2];
  float* out = (float*)d_out;

  char* ws = (char*)d_ws;
  size_t off = 0;
  auto alloc = [&](size_t bytes) {
    char* p = ws + off;
    off += (bytes + 255) & ~(size_t)255;
    return p;
  };
  __bf16* xb     = (__bf16*)alloc((size_t)M_ * C_ * 2);          // 8 MB
  __bf16* wqkvT  = (__bf16*)alloc((size_t)NQKV_ * C_ * 2);       // 3 MB
  __bf16* wprojT = (__bf16*)alloc((size_t)C_ * C_ * 2);          // 2 MB
  float*  cosT   = (float*)alloc((size_t)T_ * 32 * 4);
  float*  sinT   = (float*)alloc((size_t)T_ * 32 * 4);
  __bf16* qkv    = (__bf16*)alloc((size_t)M_ * NQKV_ * 2);       // 12.6 MB (bf16)
  __bf16* Qb     = (__bf16*)alloc((size_t)B_ * NH_ * T_ * HD_ * 2);
  __bf16* Kb     = (__bf16*)alloc((size_t)B_ * NKV_ * T_ * HD_ * 2);
  __bf16* Vt     = (__bf16*)alloc((size_t)B_ * NKV_ * T_ * HD_ * 2);
  __bf16* Yb     = (__bf16*)alloc((size_t)M_ * C_ * 2);          // 8 MB

  hipLaunchKernelGGL(cast_x_kernel, dim3(M_ * C_ / 4 / 256), dim3(256), 0, stream, x, xb);
  hipLaunchKernelGGL(transpose_cast_kernel, dim3(NQKV_ / 64, C_ / 64), dim3(256), 0, stream,
                     Wqkv, wqkvT, C_, NQKV_);
  hipLaunchKernelGGL(transpose_cast_kernel, dim3(C_ / 64, C_ / 64), dim3(256), 0, stream,
                     Wproj, wprojT, C_, C_);
  hipLaunchKernelGGL(rope_table_kernel, dim3(T_ * 32 / 256), dim3(256), 0, stream, cosT, sinT);
  hipLaunchKernelGGL(HIP_KERNEL_NAME(gemm_tn_kernel<__bf16>), dim3(NQKV_ / 64, M_ / 128),
                     dim3(256), 0, stream, xb, wqkvT, qkv, NQKV_, C_);
  hipLaunchKernelGGL(rope_qk_kernel, dim3(M_ * (NH_ + NKV_) * 8 / 256), dim3(256), 0, stream,
                     qkv, cosT, sinT, Qb, Kb);
  hipLaunchKernelGGL(v_transpose_kernel, dim3(B_ * NKV_ * (T_ / 64)), dim3(256), 0, stream,
                     qkv, Vt);
  hipLaunchKernelGGL(attn_kernel, dim3(16 * B_ * NH_), dim3(256), 0, stream, Qb, Kb, Vt, Yb);
  hipLaunchKernelGGL(HIP_KERNEL_NAME(gemm_tn_kernel<float>), dim3(C_ / 64, M_ / 128),
                     dim3(256), 0, stream, Yb, wprojT, out, C_, C_);
}